// Round 1
// baseline (1037.056 us; speedup 1.0000x reference)
//
#include <hip/hip_runtime.h>

// QuantizedLinear: out[b,s,o] = sum_k x[b,s,k] * qw[o,k]
// qw in {-2,-1,0,1,2}/(9*alpha)  ->  bf16 MFMA GEMM on Wint + hi/lo split of x.
//
// M=16384 (8*2048), N=4096 (out), K=4096 (in). All fp32 in/out.
//
// Pipeline:
//   quant_w_kernel : W fp32 -> Wint bf16 (values -2..2), K-chunk XOR-swizzled
//   split_x_kernel : X fp32 -> Xhi,Xlo bf16 planes, K-chunk XOR-swizzled
//   qgemm_kernel   : 128x128 tile, BK=64, global_load_lds(16B) staging,
//                    swizzled ds_read_b128 fragments, acc += Ahi*B + Alo*B
// Fallback (ws too small): plain fp32 LDS-tiled GEMM with on-the-fly quant.

typedef unsigned short u16;
typedef unsigned int u32;
typedef __bf16 bf16x8 __attribute__((ext_vector_type(8)));
typedef float f32x4 __attribute__((ext_vector_type(4)));

#define MDIM 16384
#define NDIM 4096
#define KDIM 4096

// ---------- helpers ----------

__device__ __forceinline__ u16 f2bf(float x) {
  // round-to-nearest-even fp32 -> bf16 (no NaN in this workload)
  u32 u = __float_as_uint(x);
  return (u16)((u + 0x7FFFu + ((u >> 16) & 1u)) >> 16);
}

__device__ __forceinline__ float quant_wint(float w, float alpha) {
  // nearest of {3.5,4.0,4.5,5.0,5.5} to 4.5*(1+w*alpha); argmin tie -> lower level.
  float tv = 4.5f * (1.0f + w * alpha);
  float u = (tv - 3.5f) * 2.0f;     // exact in fp32 for tv >= 1.75
  float f = ceilf(u - 0.5f);        // tie at u = i+0.5 -> i (lower)
  f = fminf(fmaxf(f, 0.0f), 4.0f);
  return f - 2.0f;                  // Wint in {-2..2}; final scale 1/(9*alpha) in epilogue
}

__device__ __forceinline__ void gld16(const void* g, void* l) {
  __builtin_amdgcn_global_load_lds(
      (const __attribute__((address_space(1))) void*)g,
      (__attribute__((address_space(3))) void*)l, 16, 0, 0);
}

// ---------- prepass: quantize weight, swizzled store ----------
// dst elem index: n*4096 + ((bw & ~7) | ((bw&7) ^ (n&7)))*8 + j   (bw = k/8)

__global__ void quant_w_kernel(const float4* __restrict__ W,
                               const float* __restrict__ pAlpha,
                               u16* __restrict__ Wq) {
  float alpha = pAlpha[0];
  u32 g = blockIdx.x * 256u + threadIdx.x;      // 8-elem block id, total 2097152
  u32 n = g >> 9, bw = g & 511u;
  u32 dbw = (bw & ~7u) | ((bw & 7u) ^ (n & 7u));
  float4 a = W[(size_t)g * 2];
  float4 b = W[(size_t)g * 2 + 1];
  float v[8] = {a.x, a.y, a.z, a.w, b.x, b.y, b.z, b.w};
  u32 o[4];
#pragma unroll
  for (int p = 0; p < 4; ++p) {
    u16 l0 = f2bf(quant_wint(v[2 * p], alpha));
    u16 l1 = f2bf(quant_wint(v[2 * p + 1], alpha));
    o[p] = (u32)l0 | ((u32)l1 << 16);
  }
  *(uint4*)&Wq[(size_t)n * 4096 + (size_t)dbw * 8] = make_uint4(o[0], o[1], o[2], o[3]);
}

// ---------- prepass: split x into hi/lo bf16 planes, swizzled store ----------

__global__ void split_x_kernel(const float4* __restrict__ X,
                               u16* __restrict__ Hi, u16* __restrict__ Lo) {
  u32 g = blockIdx.x * 256u + threadIdx.x;      // 8-elem block id, total 8388608
  u32 m = g >> 9, bw = g & 511u;
  u32 dbw = (bw & ~7u) | ((bw & 7u) ^ (m & 7u));
  float4 a = X[(size_t)g * 2];
  float4 b = X[(size_t)g * 2 + 1];
  float v[8] = {a.x, a.y, a.z, a.w, b.x, b.y, b.z, b.w};
  u32 oh[4], ol[4];
#pragma unroll
  for (int p = 0; p < 4; ++p) {
    u16 h0 = f2bf(v[2 * p]);
    u16 h1 = f2bf(v[2 * p + 1]);
    float hf0 = __uint_as_float((u32)h0 << 16);
    float hf1 = __uint_as_float((u32)h1 << 16);
    u16 l0 = f2bf(v[2 * p] - hf0);      // x - hi is exact (Sterbenz)
    u16 l1 = f2bf(v[2 * p + 1] - hf1);
    oh[p] = (u32)h0 | ((u32)h1 << 16);
    ol[p] = (u32)l0 | ((u32)l1 << 16);
  }
  size_t dst = (size_t)m * 4096 + (size_t)dbw * 8;
  *(uint4*)&Hi[dst] = make_uint4(oh[0], oh[1], oh[2], oh[3]);
  *(uint4*)&Lo[dst] = make_uint4(ol[0], ol[1], ol[2], ol[3]);
}

// ---------- main GEMM ----------
// 128x128 tile, BK=64, 256 threads (4 waves, 2x2), 4x4 16x16x32 frags/wave.

#define BM 128
#define BN 128
#define BK 64

__global__ __launch_bounds__(256, 3) void qgemm_kernel(
    const u16* __restrict__ Xhi, const u16* __restrict__ Xlo,
    const u16* __restrict__ Wq, const float* __restrict__ pAlpha,
    float* __restrict__ out) {
  __shared__ __align__(16) u16 Ah[BM * BK];
  __shared__ __align__(16) u16 Al[BM * BK];
  __shared__ __align__(16) u16 Bs[BN * BK];

  const int t = threadIdx.x;
  const int lane = t & 63;
  const int wave = t >> 6;
  // XCD-chunked swizzle: nwg=4096, 8 XCDs, 512 per chunk
  const int bid = blockIdx.x;
  const int nid = (bid & 7) * 512 + (bid >> 3);
  const int m_idx = nid >> 5;          // 128 M-tiles
  const int n_idx = nid & 31;          // 32 N-tiles (consecutive nid share A panel)
  const int m0 = m_idx * BM, n0 = n_idx * BN;
  const int wm = wave >> 1, wn = wave & 1;

  const float alpha = pAlpha[0];

  f32x4 acc[4][4] = {};

  // staging: thread t covers row (t>>3) of a 32-row chunk, 8 elems at col (t&7)*8
  const int srow = t >> 3;
  const int scol = (t & 7) * 8;
  const u16* gA = Xhi + (size_t)(m0 + srow) * KDIM + scol;
  const u16* gL = Xlo + (size_t)(m0 + srow) * KDIM + scol;
  const u16* gB = Wq + (size_t)(n0 + srow) * KDIM + scol;
  char* ldsA = (char*)Ah + wave * 1024;
  char* ldsL = (char*)Al + wave * 1024;
  char* ldsB = (char*)Bs + wave * 1024;

  for (int kt = 0; kt < KDIM; kt += BK) {
#pragma unroll
    for (int i = 0; i < 4; ++i) {
      gld16(gA + (size_t)i * 32 * KDIM + kt, ldsA + i * 4096);
      gld16(gL + (size_t)i * 32 * KDIM + kt, ldsL + i * 4096);
      gld16(gB + (size_t)i * 32 * KDIM + kt, ldsB + i * 4096);
    }
    __syncthreads();   // compiler drains vmcnt before s_barrier

#pragma unroll
    for (int s = 0; s < 2; ++s) {
      const int kb = s * 64 + (lane >> 4) * 16;   // byte offset of this lane's k-slice
      bf16x8 bq[4], ah[4], al[4];
#pragma unroll
      for (int j = 0; j < 4; ++j) {
        int row = wn * 64 + j * 16 + (lane & 15);
        bq[j] = *(const bf16x8*)((const char*)Bs + row * 128 + (kb ^ ((row & 7) << 4)));
      }
#pragma unroll
      for (int i = 0; i < 4; ++i) {
        int row = wm * 64 + i * 16 + (lane & 15);
        int a = row * 128 + (kb ^ ((row & 7) << 4));
        ah[i] = *(const bf16x8*)((const char*)Ah + a);
        al[i] = *(const bf16x8*)((const char*)Al + a);
      }
#pragma unroll
      for (int i = 0; i < 4; ++i)
#pragma unroll
        for (int j = 0; j < 4; ++j) {
          acc[i][j] = __builtin_amdgcn_mfma_f32_16x16x32_bf16(ah[i], bq[j], acc[i][j], 0, 0, 0);
          acc[i][j] = __builtin_amdgcn_mfma_f32_16x16x32_bf16(al[i], bq[j], acc[i][j], 0, 0, 0);
        }
    }
    __syncthreads();
  }

  const float scale = 1.0f / (9.0f * alpha);   // qw = Wint/(9*alpha)
#pragma unroll
  for (int i = 0; i < 4; ++i) {
    int row = m0 + wm * 64 + i * 16 + (lane >> 4) * 4;
#pragma unroll
    for (int j = 0; j < 4; ++j) {
      int col = n0 + wn * 64 + j * 16 + (lane & 15);
#pragma unroll
      for (int r = 0; r < 4; ++r)
        out[(size_t)(row + r) * NDIM + col] = acc[i][j][r] * scale;
    }
  }
}

// ---------- fallback (ws too small): fp32 tiled GEMM, quant on the fly ----------

__global__ void fb_gemm_kernel(const float* __restrict__ X, const float* __restrict__ W,
                               const float* __restrict__ pAlpha, float* __restrict__ out) {
  __shared__ float As[64][17];
  __shared__ float Ws[64][17];
  const float alpha = pAlpha[0];
  const float scale = 1.0f / (9.0f * alpha);
  const int bm = blockIdx.x >> 6, bn = blockIdx.x & 63;
  const int t = threadIdx.x;
  const int tx = t & 15, ty = t >> 4;
  float acc[4][4] = {};
  for (int k0 = 0; k0 < KDIM; k0 += 16) {
    int r = t >> 2;
#pragma unroll
    for (int i = 0; i < 4; ++i) {
      int c = (t & 3) * 4 + i;
      As[r][c] = X[(size_t)(bm * 64 + r) * KDIM + k0 + c];
      float w = W[(size_t)(bn * 64 + r) * KDIM + k0 + c];
      Ws[r][c] = quant_wint(w, alpha) * scale;
    }
    __syncthreads();
#pragma unroll
    for (int kk = 0; kk < 16; ++kk)
#pragma unroll
      for (int i = 0; i < 4; ++i)
#pragma unroll
        for (int j = 0; j < 4; ++j)
          acc[i][j] += As[ty * 4 + i][kk] * Ws[tx * 4 + j][kk];
    __syncthreads();
  }
#pragma unroll
  for (int i = 0; i < 4; ++i)
#pragma unroll
    for (int j = 0; j < 4; ++j)
      out[(size_t)(bm * 64 + ty * 4 + i) * NDIM + bn * 64 + tx * 4 + j] = acc[i][j];
}

// ---------- launch ----------

extern "C" void kernel_launch(void* const* d_in, const int* in_sizes, int n_in,
                              void* d_out, int out_size, void* d_ws, size_t ws_size,
                              hipStream_t stream) {
  const float* x = (const float*)d_in[0];       // [16384,4096]
  const float* w = (const float*)d_in[1];       // [4096,4096]
  const float* alpha = (const float*)d_in[2];   // scalar
  float* out = (float*)d_out;

  const size_t WQ_BYTES = (size_t)NDIM * KDIM * 2;          // 33.5 MB
  const size_t XP_BYTES = (size_t)MDIM * KDIM * 2;          // 134 MB per plane
  const size_t NEED = WQ_BYTES + 2 * XP_BYTES;              // 288 MiB

  if (ws_size >= NEED) {
    u16* Wq  = (u16*)d_ws;
    u16* Xhi = (u16*)((char*)d_ws + WQ_BYTES);
    u16* Xlo = (u16*)((char*)d_ws + WQ_BYTES + XP_BYTES);
    quant_w_kernel<<<(NDIM * KDIM / 8) / 256, 256, 0, stream>>>(
        (const float4*)w, alpha, Wq);
    split_x_kernel<<<(MDIM * KDIM / 8) / 256, 256, 0, stream>>>(
        (const float4*)x, Xhi, Xlo);
    qgemm_kernel<<<(MDIM / BM) * (NDIM / BN), 256, 0, stream>>>(
        Xhi, Xlo, Wq, alpha, out);
  } else {
    fb_gemm_kernel<<<(MDIM / 64) * (NDIM / 64), 256, 0, stream>>>(x, w, alpha, out);
  }
}

// Round 2
// 729.734 us; speedup vs baseline: 1.4211x; 1.4211x over previous
//
#include <hip/hip_runtime.h>

// QuantizedLinear: out[b,s,o] = sum_k x[b,s,k] * qw[o,k]
// qw in {-2,-1,0,1,2}/(9*alpha) -> single-plane fp16 MFMA GEMM:
//   Wint exact in fp16; x rounded to fp16 (error ~2^-11 rel, absmax ~0.014
//   vs threshold 1.2; dominant absmax term is reference tie-flip, dtype-indep).
//
// M=16384 (8*2048), N=4096 (out), K=4096 (in). fp32 in/out.
//
// Pipeline:
//   quant_w_kernel : W fp32 -> Wint fp16 (values -2..2), K-chunk XOR-swizzled
//   cvt_x_kernel   : X fp32 -> fp16, K-chunk XOR-swizzled
//   qgemm_kernel   : 128x128 tile, BK=64, global_load_lds(16B) staging,
//                    swizzled ds_read_b128 fragments, f16 MFMA
// Fallback (ws too small): plain fp32 LDS-tiled GEMM with on-the-fly quant.

typedef unsigned short u16;
typedef unsigned int u32;
typedef _Float16 f16x8 __attribute__((ext_vector_type(8)));
typedef float f32x4 __attribute__((ext_vector_type(4)));

#define MDIM 16384
#define NDIM 4096
#define KDIM 4096

// ---------- helpers ----------

__device__ __forceinline__ u16 f2h(float x) {
  _Float16 h = (_Float16)x;   // RTNE f32->f16
  return __builtin_bit_cast(u16, h);
}

__device__ __forceinline__ float quant_wint(float w, float alpha) {
  // nearest of {3.5,4.0,4.5,5.0,5.5} to 4.5*(1+w*alpha); argmin tie -> lower level.
  float tv = 4.5f * (1.0f + w * alpha);
  float u = (tv - 3.5f) * 2.0f;     // exact in fp32 for tv >= 1.75
  float f = ceilf(u - 0.5f);        // tie at u = i+0.5 -> i (lower)
  f = fminf(fmaxf(f, 0.0f), 4.0f);
  return f - 2.0f;                  // Wint in {-2..2}; final scale 1/(9*alpha) in epilogue
}

__device__ __forceinline__ void gld16(const void* g, void* l) {
  __builtin_amdgcn_global_load_lds(
      (const __attribute__((address_space(1))) void*)g,
      (__attribute__((address_space(3))) void*)l, 16, 0, 0);
}

// ---------- prepass: quantize weight, swizzled store ----------
// dst elem index: n*4096 + ((bw & ~7) | ((bw&7) ^ (n&7)))*8 + j   (bw = k/8)

__global__ void quant_w_kernel(const float4* __restrict__ W,
                               const float* __restrict__ pAlpha,
                               u16* __restrict__ Wq) {
  float alpha = pAlpha[0];
  u32 g = blockIdx.x * 256u + threadIdx.x;      // 8-elem block id, total 2097152
  u32 n = g >> 9, bw = g & 511u;
  u32 dbw = (bw & ~7u) | ((bw & 7u) ^ (n & 7u));
  float4 a = W[(size_t)g * 2];
  float4 b = W[(size_t)g * 2 + 1];
  float v[8] = {a.x, a.y, a.z, a.w, b.x, b.y, b.z, b.w};
  u32 o[4];
#pragma unroll
  for (int p = 0; p < 4; ++p) {
    u16 l0 = f2h(quant_wint(v[2 * p], alpha));
    u16 l1 = f2h(quant_wint(v[2 * p + 1], alpha));
    o[p] = (u32)l0 | ((u32)l1 << 16);
  }
  *(uint4*)&Wq[(size_t)n * 4096 + (size_t)dbw * 8] = make_uint4(o[0], o[1], o[2], o[3]);
}

// ---------- prepass: x -> fp16, swizzled store ----------

__global__ void cvt_x_kernel(const float4* __restrict__ X, u16* __restrict__ Xh) {
  u32 g = blockIdx.x * 256u + threadIdx.x;      // 8-elem block id, total 8388608
  u32 m = g >> 9, bw = g & 511u;
  u32 dbw = (bw & ~7u) | ((bw & 7u) ^ (m & 7u));
  float4 a = X[(size_t)g * 2];
  float4 b = X[(size_t)g * 2 + 1];
  float v[8] = {a.x, a.y, a.z, a.w, b.x, b.y, b.z, b.w};
  u32 oh[4];
#pragma unroll
  for (int p = 0; p < 4; ++p) {
    u16 h0 = f2h(v[2 * p]);
    u16 h1 = f2h(v[2 * p + 1]);
    oh[p] = (u32)h0 | ((u32)h1 << 16);
  }
  *(uint4*)&Xh[(size_t)m * 4096 + (size_t)dbw * 8] = make_uint4(oh[0], oh[1], oh[2], oh[3]);
}

// ---------- main GEMM ----------
// 128x128 tile, BK=64, 256 threads (4 waves, 2x2), 4x4 16x16x32 f16 frags/wave.

#define BM 128
#define BN 128
#define BK 64

__global__ __launch_bounds__(256, 4) void qgemm_kernel(
    const u16* __restrict__ Xh, const u16* __restrict__ Wq,
    const float* __restrict__ pAlpha, float* __restrict__ out) {
  __shared__ __align__(16) u16 As[BM * BK];
  __shared__ __align__(16) u16 Bs[BN * BK];

  const int t = threadIdx.x;
  const int lane = t & 63;
  const int wave = t >> 6;
  // XCD-chunked swizzle: nwg=4096, 8 XCDs, 512 per chunk
  const int bid = blockIdx.x;
  const int nid = (bid & 7) * 512 + (bid >> 3);
  const int m_idx = nid >> 5;          // 128 M-tiles
  const int n_idx = nid & 31;          // 32 N-tiles (consecutive nid share A panel)
  const int m0 = m_idx * BM, n0 = n_idx * BN;
  const int wm = wave >> 1, wn = wave & 1;

  const float alpha = pAlpha[0];

  f32x4 acc[4][4] = {};

  // staging: thread t covers row (t>>3) of a 32-row chunk, 8 elems at col (t&7)*8
  const int srow = t >> 3;
  const int scol = (t & 7) * 8;
  const u16* gA = Xh + (size_t)(m0 + srow) * KDIM + scol;
  const u16* gB = Wq + (size_t)(n0 + srow) * KDIM + scol;
  char* ldsA = (char*)As + wave * 1024;
  char* ldsB = (char*)Bs + wave * 1024;

  for (int kt = 0; kt < KDIM; kt += BK) {
#pragma unroll
    for (int i = 0; i < 4; ++i) {
      gld16(gA + (size_t)i * 32 * KDIM + kt, ldsA + i * 4096);
      gld16(gB + (size_t)i * 32 * KDIM + kt, ldsB + i * 4096);
    }
    __syncthreads();   // compiler drains vmcnt before s_barrier

#pragma unroll
    for (int s = 0; s < 2; ++s) {
      const int kb = s * 64 + (lane >> 4) * 16;   // byte offset of this lane's k-slice
      f16x8 bq[4], ah[4];
#pragma unroll
      for (int j = 0; j < 4; ++j) {
        int row = wn * 64 + j * 16 + (lane & 15);
        bq[j] = *(const f16x8*)((const char*)Bs + row * 128 + (kb ^ ((row & 7) << 4)));
      }
#pragma unroll
      for (int i = 0; i < 4; ++i) {
        int row = wm * 64 + i * 16 + (lane & 15);
        ah[i] = *(const f16x8*)((const char*)As + row * 128 + (kb ^ ((row & 7) << 4)));
      }
#pragma unroll
      for (int i = 0; i < 4; ++i)
#pragma unroll
        for (int j = 0; j < 4; ++j)
          acc[i][j] = __builtin_amdgcn_mfma_f32_16x16x32_f16(ah[i], bq[j], acc[i][j], 0, 0, 0);
    }
    __syncthreads();
  }

  const float scale = 1.0f / (9.0f * alpha);   // qw = Wint/(9*alpha)
#pragma unroll
  for (int i = 0; i < 4; ++i) {
    int row = m0 + wm * 64 + i * 16 + (lane >> 4) * 4;
#pragma unroll
    for (int j = 0; j < 4; ++j) {
      int col = n0 + wn * 64 + j * 16 + (lane & 15);
#pragma unroll
      for (int r = 0; r < 4; ++r)
        out[(size_t)(row + r) * NDIM + col] = acc[i][j][r] * scale;
    }
  }
}

// ---------- fallback (ws too small): fp32 tiled GEMM, quant on the fly ----------

__global__ void fb_gemm_kernel(const float* __restrict__ X, const float* __restrict__ W,
                               const float* __restrict__ pAlpha, float* __restrict__ out) {
  __shared__ float As[64][17];
  __shared__ float Ws[64][17];
  const float alpha = pAlpha[0];
  const float scale = 1.0f / (9.0f * alpha);
  const int bm = blockIdx.x >> 6, bn = blockIdx.x & 63;
  const int t = threadIdx.x;
  const int tx = t & 15, ty = t >> 4;
  float acc[4][4] = {};
  for (int k0 = 0; k0 < KDIM; k0 += 16) {
    int r = t >> 2;
#pragma unroll
    for (int i = 0; i < 4; ++i) {
      int c = (t & 3) * 4 + i;
      As[r][c] = X[(size_t)(bm * 64 + r) * KDIM + k0 + c];
      float w = W[(size_t)(bn * 64 + r) * KDIM + k0 + c];
      Ws[r][c] = quant_wint(w, alpha) * scale;
    }
    __syncthreads();
#pragma unroll
    for (int kk = 0; kk < 16; ++kk)
#pragma unroll
      for (int i = 0; i < 4; ++i)
#pragma unroll
        for (int j = 0; j < 4; ++j)
          acc[i][j] += As[ty * 4 + i][kk] * Ws[tx * 4 + j][kk];
    __syncthreads();
  }
#pragma unroll
  for (int i = 0; i < 4; ++i)
#pragma unroll
    for (int j = 0; j < 4; ++j)
      out[(size_t)(bm * 64 + ty * 4 + i) * NDIM + bn * 64 + tx * 4 + j] = acc[i][j];
}

// ---------- launch ----------

extern "C" void kernel_launch(void* const* d_in, const int* in_sizes, int n_in,
                              void* d_out, int out_size, void* d_ws, size_t ws_size,
                              hipStream_t stream) {
  const float* x = (const float*)d_in[0];       // [16384,4096]
  const float* w = (const float*)d_in[1];       // [4096,4096]
  const float* alpha = (const float*)d_in[2];   // scalar
  float* out = (float*)d_out;

  const size_t WQ_BYTES = (size_t)NDIM * KDIM * 2;          // 33.5 MB
  const size_t XP_BYTES = (size_t)MDIM * KDIM * 2;          // 134 MB
  const size_t NEED = WQ_BYTES + XP_BYTES;                  // ~168 MB

  if (ws_size >= NEED) {
    u16* Wq = (u16*)d_ws;
    u16* Xh = (u16*)((char*)d_ws + WQ_BYTES);
    quant_w_kernel<<<(NDIM * KDIM / 8) / 256, 256, 0, stream>>>(
        (const float4*)w, alpha, Wq);
    cvt_x_kernel<<<(MDIM * KDIM / 8) / 256, 256, 0, stream>>>(
        (const float4*)x, Xh);
    qgemm_kernel<<<(MDIM / BM) * (NDIM / BN), 256, 0, stream>>>(
        Xh, Wq, alpha, out);
  } else {
    fb_gemm_kernel<<<(MDIM / 64) * (NDIM / 64), 256, 0, stream>>>(x, w, alpha, out);
  }
}

// Round 3
// 551.469 us; speedup vs baseline: 1.8805x; 1.3233x over previous
//
#include <hip/hip_runtime.h>

// QuantizedLinear: out[b,s,o] = sum_k x[b,s,k] * qw[o,k]
// qw in {-2,-1,0,1,2}/(9*alpha) -> single-plane fp16 MFMA GEMM.
// M=16384, N=4096, K=4096. fp32 in/out.
//
// R3: 256x256 8-phase counted-vmcnt schedule (T2+T3+T4+T5):
//   512 thr (8 waves, 2Mx4N), BK=64, 128KiB LDS double-buffer,
//   per-wave acc[8][4] (128x64 out), interleaved frag->half mapping so
//   half-tile deadlines stagger; stage 1 half-tile/phase; vmcnt(4) at
//   phases 1/4/5/8 only (never 0); setprio around MFMA clusters.
// Prepasses unchanged (K-chunk XOR pre-swizzled global layout -> linear
// global_load_lds + swizzled ds_read_b128, 0 bank conflicts measured).

typedef unsigned short u16;
typedef unsigned int u32;
typedef _Float16 f16x8 __attribute__((ext_vector_type(8)));
typedef float f32x4 __attribute__((ext_vector_type(4)));

#define MDIM 16384
#define NDIM 4096
#define KDIM 4096

// ---------- helpers ----------

__device__ __forceinline__ u16 f2h(float x) {
  _Float16 h = (_Float16)x;   // RTNE f32->f16
  return __builtin_bit_cast(u16, h);
}

__device__ __forceinline__ float quant_wint(float w, float alpha) {
  // nearest of {3.5,4.0,4.5,5.0,5.5} to 4.5*(1+w*alpha); argmin tie -> lower level.
  float tv = 4.5f * (1.0f + w * alpha);
  float u = (tv - 3.5f) * 2.0f;
  float f = ceilf(u - 0.5f);
  f = fminf(fmaxf(f, 0.0f), 4.0f);
  return f - 2.0f;                  // Wint in {-2..2}; scale 1/(9*alpha) in epilogue
}

__device__ __forceinline__ void gld16(const void* g, void* l) {
  __builtin_amdgcn_global_load_lds(
      (const __attribute__((address_space(1))) void*)g,
      (__attribute__((address_space(3))) void*)l, 16, 0, 0);
}

// ---------- prepass: quantize weight, swizzled store ----------

__global__ void quant_w_kernel(const float4* __restrict__ W,
                               const float* __restrict__ pAlpha,
                               u16* __restrict__ Wq) {
  float alpha = pAlpha[0];
  u32 g = blockIdx.x * 256u + threadIdx.x;
  u32 n = g >> 9, bw = g & 511u;
  u32 dbw = (bw & ~7u) | ((bw & 7u) ^ (n & 7u));
  float4 a = W[(size_t)g * 2];
  float4 b = W[(size_t)g * 2 + 1];
  float v[8] = {a.x, a.y, a.z, a.w, b.x, b.y, b.z, b.w};
  u32 o[4];
#pragma unroll
  for (int p = 0; p < 4; ++p) {
    u16 l0 = f2h(quant_wint(v[2 * p], alpha));
    u16 l1 = f2h(quant_wint(v[2 * p + 1], alpha));
    o[p] = (u32)l0 | ((u32)l1 << 16);
  }
  *(uint4*)&Wq[(size_t)n * 4096 + (size_t)dbw * 8] = make_uint4(o[0], o[1], o[2], o[3]);
}

// ---------- prepass: x -> fp16, swizzled store ----------

__global__ void cvt_x_kernel(const float4* __restrict__ X, u16* __restrict__ Xh) {
  u32 g = blockIdx.x * 256u + threadIdx.x;
  u32 m = g >> 9, bw = g & 511u;
  u32 dbw = (bw & ~7u) | ((bw & 7u) ^ (m & 7u));
  float4 a = X[(size_t)g * 2];
  float4 b = X[(size_t)g * 2 + 1];
  float v[8] = {a.x, a.y, a.z, a.w, b.x, b.y, b.z, b.w};
  u32 oh[4];
#pragma unroll
  for (int p = 0; p < 4; ++p) {
    u16 h0 = f2h(v[2 * p]);
    u16 h1 = f2h(v[2 * p + 1]);
    oh[p] = (u32)h0 | ((u32)h1 << 16);
  }
  *(uint4*)&Xh[(size_t)m * 4096 + (size_t)dbw * 8] = make_uint4(oh[0], oh[1], oh[2], oh[3]);
}

// ---------- main GEMM: 256x256, BK=64, 8-phase counted-vmcnt ----------

#define BM 256
#define BN 256
#define BK 64
#define NKT (KDIM / BK)   // 64

__global__ __launch_bounds__(512, 2) void qgemm_kernel(
    const u16* __restrict__ Xh, const u16* __restrict__ Wq,
    const float* __restrict__ pAlpha, float* __restrict__ out) {
  // LDS: A[2][256][64] f16 (64KB) + B[2][256][64] f16 (64KB) = 128 KiB
  __shared__ __align__(16) u16 sm[65536];
  const char* smb = (const char*)sm;

  const int t512 = threadIdx.x;
  const int lane = t512 & 63;
  const int wave = t512 >> 6;
  const int wm = wave >> 2;      // 0..1
  const int wn = wave & 3;       // 0..3

  // XCD-chunked swizzle: nwg=1024, 8 XCDs, 128 per chunk
  const int bid = blockIdx.x;
  const int nid = (bid & 7) * 128 + (bid >> 3);
  const int m_idx = nid >> 4;    // 64 M-tiles
  const int n_idx = nid & 15;    // 16 N-tiles (consecutive nid share A panel)
  const int m0 = m_idx * BM, n0 = n_idx * BN;

  const float alpha = pAlpha[0];

  f32x4 acc[8][4] = {};
  f16x8 bfr[4];

  const int kb = (lane >> 4) << 4;     // byte offset of k-group within 128B row
  const int swz = (lane & 7) << 4;     // XOR swizzle (matches prepass layout)

  // frag row maps (interleaved across halves: mi>>2 / nj>>1 select the half)
#define AROW(MI) (wm * 64 + ((MI) >> 2) * 128 + ((MI)&3) * 16 + (lane & 15))
#define BROW(NJ) (wn * 32 + ((NJ) >> 1) * 128 + ((NJ)&1) * 16 + (lane & 15))
#define LDA(P, MI, KS) \
  (*(const f16x8*)(smb + (P)*32768 + AROW(MI) * 128 + ((((KS)*64) + kb) ^ swz)))
#define LDB(P, NJ, KS) \
  (*(const f16x8*)(smb + 65536 + (P)*32768 + BROW(NJ) * 128 + ((((KS)*64) + kb) ^ swz)))

  // LDS element offsets for staging (u16 elems)
#define AELEM(P, H) ((P)*16384 + (H)*8192)
#define BELEM(P, H) (32768 + (P)*16384 + (H)*8192)
  // global row-block bases for half-tiles of k-tile KT (wrapped; junk tail never read)
#define GA(KT, H) (Xh + (size_t)(m0 + (H)*128) * 4096 + (size_t)(((KT)&63)) * 64)
#define GB(KT, H) (Wq + (size_t)(n0 + (H)*128) * 4096 + (size_t)(((KT)&63)) * 64)

  // stage one 128x64 half-tile: 2 x global_load_lds(16B), linear dest
#define STAGE(GBASE, LELEM) do { \
    const u16* _g = (GBASE) + (size_t)(wave * 8 + (lane >> 3)) * 4096 + (size_t)((lane & 7) * 8); \
    gld16(_g, (void*)(sm + (LELEM) + wave * 512)); \
    gld16(_g + (size_t)64 * 4096, (void*)(sm + (LELEM) + 4096 + wave * 512)); \
  } while (0)

#define ACCROW(MI, AV) do { \
    acc[MI][0] = __builtin_amdgcn_mfma_f32_16x16x32_f16(AV, bfr[0], acc[MI][0], 0, 0, 0); \
    acc[MI][1] = __builtin_amdgcn_mfma_f32_16x16x32_f16(AV, bfr[1], acc[MI][1], 0, 0, 0); \
    acc[MI][2] = __builtin_amdgcn_mfma_f32_16x16x32_f16(AV, bfr[2], acc[MI][2], 0, 0, 0); \
    acc[MI][3] = __builtin_amdgcn_mfma_f32_16x16x32_f16(AV, bfr[3], acc[MI][3], 0, 0, 0); \
  } while (0)

#define VM4 asm volatile("s_waitcnt vmcnt(4)" ::: "memory")
#define VMN ((void)0)

  // phase: {ds_read subtile; stage 1 half-tile} -> barrier -> lgkm(0) ->
  //        setprio(1) 16xMFMA setprio(0) -> [vmcnt(4)] -> barrier
#define PHASE(P, KS, MH, READB, SG, SL, WAITVM) do { \
    if (READB) { \
      bfr[0] = LDB(P, 0, KS); bfr[1] = LDB(P, 1, KS); \
      bfr[2] = LDB(P, 2, KS); bfr[3] = LDB(P, 3, KS); \
    } \
    f16x8 a0 = LDA(P, (MH)*4 + 0, KS); \
    f16x8 a1 = LDA(P, (MH)*4 + 1, KS); \
    f16x8 a2 = LDA(P, (MH)*4 + 2, KS); \
    f16x8 a3 = LDA(P, (MH)*4 + 3, KS); \
    STAGE(SG, SL); \
    __builtin_amdgcn_sched_barrier(0); \
    __builtin_amdgcn_s_barrier(); \
    asm volatile("s_waitcnt lgkmcnt(0)" ::: "memory"); \
    __builtin_amdgcn_sched_barrier(0); \
    __builtin_amdgcn_s_setprio(1); \
    ACCROW((MH)*4 + 0, a0); ACCROW((MH)*4 + 1, a1); \
    ACCROW((MH)*4 + 2, a2); ACCROW((MH)*4 + 3, a3); \
    __builtin_amdgcn_s_setprio(0); \
    WAITVM; \
    __builtin_amdgcn_s_barrier(); \
  } while (0)

  // prologue: B0(0),B1(0),A0(0),A1(0) -> buf0; B0(1) -> buf1  (10 loads)
  STAGE(GB(0, 0), BELEM(0, 0));
  STAGE(GB(0, 1), BELEM(0, 1));
  STAGE(GA(0, 0), AELEM(0, 0));
  STAGE(GA(0, 1), AELEM(0, 1));
  STAGE(GB(1, 0), BELEM(1, 0));
  asm volatile("s_waitcnt vmcnt(4)" ::: "memory");   // tile0's B0,B1,A0 landed
  __builtin_amdgcn_s_barrier();

#pragma unroll 1
  for (int t = 0; t < NKT; t += 2) {
    // tile t in buf0; stage into buf1 (B1,A0,A1 of t+1) + buf0 (B0 of t+2)
    PHASE(0, 0, 0, 1, GB(t + 1, 1), BELEM(1, 1), VM4);
    PHASE(0, 0, 1, 0, GA(t + 1, 0), AELEM(1, 0), VMN);
    PHASE(0, 1, 0, 1, GA(t + 1, 1), AELEM(1, 1), VMN);
    PHASE(0, 1, 1, 0, GB(t + 2, 0), BELEM(0, 0), VM4);
    // tile t+1 in buf1
    PHASE(1, 0, 0, 1, GB(t + 2, 1), BELEM(0, 1), VM4);
    PHASE(1, 0, 1, 0, GA(t + 2, 0), AELEM(0, 0), VMN);
    PHASE(1, 1, 0, 1, GA(t + 2, 1), AELEM(0, 1), VMN);
    PHASE(1, 1, 1, 0, GB(t + 3, 0), BELEM(1, 0), VM4);
  }

  // epilogue
  const float scale = 1.0f / (9.0f * alpha);
#pragma unroll
  for (int mi = 0; mi < 8; ++mi) {
    int row = m0 + (mi >> 2) * 128 + wm * 64 + (mi & 3) * 16 + (lane >> 4) * 4;
#pragma unroll
    for (int nj = 0; nj < 4; ++nj) {
      int col = n0 + (nj >> 1) * 128 + wn * 32 + (nj & 1) * 16 + (lane & 15);
#pragma unroll
      for (int r = 0; r < 4; ++r)
        out[(size_t)(row + r) * NDIM + col] = acc[mi][nj][r] * scale;
    }
  }
#undef PHASE
#undef VM4
#undef VMN
#undef ACCROW
#undef STAGE
#undef GA
#undef GB
#undef AELEM
#undef BELEM
#undef LDA
#undef LDB
#undef AROW
#undef BROW
}

// ---------- fallback (ws too small): fp32 tiled GEMM, quant on the fly ----------

__global__ void fb_gemm_kernel(const float* __restrict__ X, const float* __restrict__ W,
                               const float* __restrict__ pAlpha, float* __restrict__ out) {
  __shared__ float As[64][17];
  __shared__ float Ws[64][17];
  const float alpha = pAlpha[0];
  const float scale = 1.0f / (9.0f * alpha);
  const int bm = blockIdx.x >> 6, bn = blockIdx.x & 63;
  const int t = threadIdx.x;
  const int tx = t & 15, ty = t >> 4;
  float acc[4][4] = {};
  for (int k0 = 0; k0 < KDIM; k0 += 16) {
    int r = t >> 2;
#pragma unroll
    for (int i = 0; i < 4; ++i) {
      int c = (t & 3) * 4 + i;
      As[r][c] = X[(size_t)(bm * 64 + r) * KDIM + k0 + c];
      float w = W[(size_t)(bn * 64 + r) * KDIM + k0 + c];
      Ws[r][c] = quant_wint(w, alpha) * scale;
    }
    __syncthreads();
#pragma unroll
    for (int kk = 0; kk < 16; ++kk)
#pragma unroll
      for (int i = 0; i < 4; ++i)
#pragma unroll
        for (int j = 0; j < 4; ++j)
          acc[i][j] += As[ty * 4 + i][kk] * Ws[tx * 4 + j][kk];
    __syncthreads();
  }
#pragma unroll
  for (int i = 0; i < 4; ++i)
#pragma unroll
    for (int j = 0; j < 4; ++j)
      out[(size_t)(bm * 64 + ty * 4 + i) * NDIM + bn * 64 + tx * 4 + j] = acc[i][j];
}

// ---------- launch ----------

extern "C" void kernel_launch(void* const* d_in, const int* in_sizes, int n_in,
                              void* d_out, int out_size, void* d_ws, size_t ws_size,
                              hipStream_t stream) {
  const float* x = (const float*)d_in[0];       // [16384,4096]
  const float* w = (const float*)d_in[1];       // [4096,4096]
  const float* alpha = (const float*)d_in[2];   // scalar
  float* out = (float*)d_out;

  const size_t WQ_BYTES = (size_t)NDIM * KDIM * 2;          // 33.5 MB
  const size_t XP_BYTES = (size_t)MDIM * KDIM * 2;          // 134 MB
  const size_t NEED = WQ_BYTES + XP_BYTES;                  // ~168 MB

  if (ws_size >= NEED) {
    u16* Wq = (u16*)d_ws;
    u16* Xh = (u16*)((char*)d_ws + WQ_BYTES);
    quant_w_kernel<<<(NDIM * KDIM / 8) / 256, 256, 0, stream>>>(
        (const float4*)w, alpha, Wq);
    cvt_x_kernel<<<(MDIM * KDIM / 8) / 256, 256, 0, stream>>>(
        (const float4*)x, Xh);
    qgemm_kernel<<<(MDIM / BM) * (NDIM / BN), 512, 0, stream>>>(
        Xh, Wq, alpha, out);
  } else {
    fb_gemm_kernel<<<(MDIM / 64) * (NDIM / 64), 256, 0, stream>>>(x, w, alpha, out);
  }
}

// Round 4
// 543.933 us; speedup vs baseline: 1.9066x; 1.0139x over previous
//
#include <hip/hip_runtime.h>

// QuantizedLinear: out[b,s,o] = sum_k x[b,s,k] * qw[o,k]
// qw in {-2,-1,0,1,2}/(9*alpha) -> single-plane bf16 MFMA GEMM.
// M=16384, N=4096, K=4096. fp32 in/out.
//
// R4: 256x256 8-phase counted-vmcnt schedule, ONE barrier per phase:
//   mid-barrier removed so per-wave lgkmcnt(0) lets early waves start MFMA
//   while other waves' ds_reads drain (LDS-drain/MFMA overlap across waves).
//   f16 -> bf16 (2075 vs 1955 TF ubench). Stage->consume ordering audited:
//   stage(s) -> vm4@q>=s+2 -> end-barrier(q) -> read@p>q holds for all slots.
// Prepasses: K-chunk XOR pre-swizzled global layout -> linear global_load_lds
// + swizzled ds_read_b128 (0 bank conflicts measured).

typedef unsigned short u16;
typedef unsigned int u32;
typedef __bf16 bf16x8 __attribute__((ext_vector_type(8)));
typedef float f32x4 __attribute__((ext_vector_type(4)));

#define MDIM 16384
#define NDIM 4096
#define KDIM 4096

// ---------- helpers ----------

__device__ __forceinline__ u16 f2bf(float x) {
  // round-to-nearest-even fp32 -> bf16 (no NaN in this workload)
  u32 u = __float_as_uint(x);
  return (u16)((u + 0x7FFFu + ((u >> 16) & 1u)) >> 16);
}

__device__ __forceinline__ float quant_wint(float w, float alpha) {
  // nearest of {3.5,4.0,4.5,5.0,5.5} to 4.5*(1+w*alpha); argmin tie -> lower level.
  float tv = 4.5f * (1.0f + w * alpha);
  float u = (tv - 3.5f) * 2.0f;
  float f = ceilf(u - 0.5f);
  f = fminf(fmaxf(f, 0.0f), 4.0f);
  return f - 2.0f;                  // Wint in {-2..2}; scale 1/(9*alpha) in epilogue
}

__device__ __forceinline__ void gld16(const void* g, void* l) {
  __builtin_amdgcn_global_load_lds(
      (const __attribute__((address_space(1))) void*)g,
      (__attribute__((address_space(3))) void*)l, 16, 0, 0);
}

// ---------- prepass: quantize weight, swizzled store ----------

__global__ void quant_w_kernel(const float4* __restrict__ W,
                               const float* __restrict__ pAlpha,
                               u16* __restrict__ Wq) {
  float alpha = pAlpha[0];
  u32 g = blockIdx.x * 256u + threadIdx.x;
  u32 n = g >> 9, bw = g & 511u;
  u32 dbw = (bw & ~7u) | ((bw & 7u) ^ (n & 7u));
  float4 a = W[(size_t)g * 2];
  float4 b = W[(size_t)g * 2 + 1];
  float v[8] = {a.x, a.y, a.z, a.w, b.x, b.y, b.z, b.w};
  u32 o[4];
#pragma unroll
  for (int p = 0; p < 4; ++p) {
    u16 l0 = f2bf(quant_wint(v[2 * p], alpha));
    u16 l1 = f2bf(quant_wint(v[2 * p + 1], alpha));
    o[p] = (u32)l0 | ((u32)l1 << 16);
  }
  *(uint4*)&Wq[(size_t)n * 4096 + (size_t)dbw * 8] = make_uint4(o[0], o[1], o[2], o[3]);
}

// ---------- prepass: x -> bf16, swizzled store ----------

__global__ void cvt_x_kernel(const float4* __restrict__ X, u16* __restrict__ Xh) {
  u32 g = blockIdx.x * 256u + threadIdx.x;
  u32 m = g >> 9, bw = g & 511u;
  u32 dbw = (bw & ~7u) | ((bw & 7u) ^ (m & 7u));
  float4 a = X[(size_t)g * 2];
  float4 b = X[(size_t)g * 2 + 1];
  float v[8] = {a.x, a.y, a.z, a.w, b.x, b.y, b.z, b.w};
  u32 oh[4];
#pragma unroll
  for (int p = 0; p < 4; ++p) {
    u16 h0 = f2bf(v[2 * p]);
    u16 h1 = f2bf(v[2 * p + 1]);
    oh[p] = (u32)h0 | ((u32)h1 << 16);
  }
  *(uint4*)&Xh[(size_t)m * 4096 + (size_t)dbw * 8] = make_uint4(oh[0], oh[1], oh[2], oh[3]);
}

// ---------- main GEMM: 256x256, BK=64, 8-phase, 1 barrier/phase ----------

#define BM 256
#define BN 256
#define BK 64
#define NKT (KDIM / BK)   // 64

__global__ __launch_bounds__(512, 2) void qgemm_kernel(
    const u16* __restrict__ Xh, const u16* __restrict__ Wq,
    const float* __restrict__ pAlpha, float* __restrict__ out) {
  // LDS: A[2][256][64] bf16 (64KB) + B[2][256][64] bf16 (64KB) = 128 KiB
  __shared__ __align__(16) u16 sm[65536];
  const char* smb = (const char*)sm;

  const int t512 = threadIdx.x;
  const int lane = t512 & 63;
  const int wave = t512 >> 6;
  const int wm = wave >> 2;      // 0..1
  const int wn = wave & 3;       // 0..3

  // XCD-chunked swizzle: nwg=1024, 8 XCDs, 128 per chunk
  const int bid = blockIdx.x;
  const int nid = (bid & 7) * 128 + (bid >> 3);
  const int m_idx = nid >> 4;    // 64 M-tiles
  const int n_idx = nid & 15;    // 16 N-tiles (consecutive nid share A panel)
  const int m0 = m_idx * BM, n0 = n_idx * BN;

  const float alpha = pAlpha[0];

  f32x4 acc[8][4] = {};
  bf16x8 bfr[4];

  const int kb = (lane >> 4) << 4;     // byte offset of k-group within 128B row
  const int swz = (lane & 7) << 4;     // XOR swizzle (matches prepass layout)

  // frag row maps (interleaved across halves: mi>>2 / nj>>1 select the half)
#define AROW(MI) (wm * 64 + ((MI) >> 2) * 128 + ((MI)&3) * 16 + (lane & 15))
#define BROW(NJ) (wn * 32 + ((NJ) >> 1) * 128 + ((NJ)&1) * 16 + (lane & 15))
#define LDA(P, MI, KS) \
  (*(const bf16x8*)(smb + (P)*32768 + AROW(MI) * 128 + ((((KS)*64) + kb) ^ swz)))
#define LDB(P, NJ, KS) \
  (*(const bf16x8*)(smb + 65536 + (P)*32768 + BROW(NJ) * 128 + ((((KS)*64) + kb) ^ swz)))

  // LDS element offsets for staging (u16 elems)
#define AELEM(P, H) ((P)*16384 + (H)*8192)
#define BELEM(P, H) (32768 + (P)*16384 + (H)*8192)
  // global row-block bases for half-tiles of k-tile KT (wrapped; junk tail never read)
#define GA(KT, H) (Xh + (size_t)(m0 + (H)*128) * 4096 + (size_t)(((KT)&63)) * 64)
#define GB(KT, H) (Wq + (size_t)(n0 + (H)*128) * 4096 + (size_t)(((KT)&63)) * 64)

  // stage one 128x64 half-tile: 2 x global_load_lds(16B), linear dest
#define STAGE(GBASE, LELEM) do { \
    const u16* _g = (GBASE) + (size_t)(wave * 8 + (lane >> 3)) * 4096 + (size_t)((lane & 7) * 8); \
    gld16(_g, (void*)(sm + (LELEM) + wave * 512)); \
    gld16(_g + (size_t)64 * 4096, (void*)(sm + (LELEM) + 4096 + wave * 512)); \
  } while (0)

#define ACCROW(MI, AV) do { \
    acc[MI][0] = __builtin_amdgcn_mfma_f32_16x16x32_bf16(AV, bfr[0], acc[MI][0], 0, 0, 0); \
    acc[MI][1] = __builtin_amdgcn_mfma_f32_16x16x32_bf16(AV, bfr[1], acc[MI][1], 0, 0, 0); \
    acc[MI][2] = __builtin_amdgcn_mfma_f32_16x16x32_bf16(AV, bfr[2], acc[MI][2], 0, 0, 0); \
    acc[MI][3] = __builtin_amdgcn_mfma_f32_16x16x32_bf16(AV, bfr[3], acc[MI][3], 0, 0, 0); \
  } while (0)

#define VM4 asm volatile("s_waitcnt vmcnt(4)" ::: "memory")
#define VMN ((void)0)

  // phase: {ds_read subtile; stage 1 half-tile} -> lgkm(0) (own reads) ->
  //        setprio(1) 16xMFMA setprio(0) -> [vmcnt(4)] -> barrier
  // NO mid-barrier: waves drift within the phase so one wave's MFMA overlaps
  // another wave's LDS drain; end-barrier bounds drift to one phase.
#define PHASE(P, KS, MH, READB, SG, SL, WAITVM) do { \
    if (READB) { \
      bfr[0] = LDB(P, 0, KS); bfr[1] = LDB(P, 1, KS); \
      bfr[2] = LDB(P, 2, KS); bfr[3] = LDB(P, 3, KS); \
    } \
    bf16x8 a0 = LDA(P, (MH)*4 + 0, KS); \
    bf16x8 a1 = LDA(P, (MH)*4 + 1, KS); \
    bf16x8 a2 = LDA(P, (MH)*4 + 2, KS); \
    bf16x8 a3 = LDA(P, (MH)*4 + 3, KS); \
    STAGE(SG, SL); \
    __builtin_amdgcn_sched_barrier(0); \
    asm volatile("s_waitcnt lgkmcnt(0)" ::: "memory"); \
    __builtin_amdgcn_sched_barrier(0); \
    __builtin_amdgcn_s_setprio(1); \
    ACCROW((MH)*4 + 0, a0); ACCROW((MH)*4 + 1, a1); \
    ACCROW((MH)*4 + 2, a2); ACCROW((MH)*4 + 3, a3); \
    __builtin_amdgcn_s_setprio(0); \
    WAITVM; \
    __builtin_amdgcn_s_barrier(); \
  } while (0)

  // prologue: B0(0),B1(0),A0(0),A1(0) -> buf0; B0(1) -> buf1  (10 loads)
  STAGE(GB(0, 0), BELEM(0, 0));
  STAGE(GB(0, 1), BELEM(0, 1));
  STAGE(GA(0, 0), AELEM(0, 0));
  STAGE(GA(0, 1), AELEM(0, 1));
  STAGE(GB(1, 0), BELEM(1, 0));
  asm volatile("s_waitcnt vmcnt(4)" ::: "memory");   // tile0's B0,B1,A0 landed
  __builtin_amdgcn_s_barrier();

#pragma unroll 1
  for (int t = 0; t < NKT; t += 2) {
    // tile t in buf0; stage into buf1 (B1,A0,A1 of t+1) + buf0 (B0 of t+2)
    PHASE(0, 0, 0, 1, GB(t + 1, 1), BELEM(1, 1), VM4);
    PHASE(0, 0, 1, 0, GA(t + 1, 0), AELEM(1, 0), VMN);
    PHASE(0, 1, 0, 1, GA(t + 1, 1), AELEM(1, 1), VMN);
    PHASE(0, 1, 1, 0, GB(t + 2, 0), BELEM(0, 0), VM4);
    // tile t+1 in buf1
    PHASE(1, 0, 0, 1, GB(t + 2, 1), BELEM(0, 1), VM4);
    PHASE(1, 0, 1, 0, GA(t + 2, 0), AELEM(0, 0), VMN);
    PHASE(1, 1, 0, 1, GA(t + 2, 1), AELEM(0, 1), VMN);
    PHASE(1, 1, 1, 0, GB(t + 3, 0), BELEM(1, 0), VM4);
  }

  // epilogue
  const float scale = 1.0f / (9.0f * alpha);
#pragma unroll
  for (int mi = 0; mi < 8; ++mi) {
    int row = m0 + (mi >> 2) * 128 + wm * 64 + (mi & 3) * 16 + (lane >> 4) * 4;
#pragma unroll
    for (int nj = 0; nj < 4; ++nj) {
      int col = n0 + (nj >> 1) * 128 + wn * 32 + (nj & 1) * 16 + (lane & 15);
#pragma unroll
      for (int r = 0; r < 4; ++r)
        out[(size_t)(row + r) * NDIM + col] = acc[mi][nj][r] * scale;
    }
  }
#undef PHASE
#undef VM4
#undef VMN
#undef ACCROW
#undef STAGE
#undef GA
#undef GB
#undef AELEM
#undef BELEM
#undef LDA
#undef LDB
#undef AROW
#undef BROW
}

// ---------- fallback (ws too small): fp32 tiled GEMM, quant on the fly ----------

__global__ void fb_gemm_kernel(const float* __restrict__ X, const float* __restrict__ W,
                               const float* __restrict__ pAlpha, float* __restrict__ out) {
  __shared__ float As[64][17];
  __shared__ float Ws[64][17];
  const float alpha = pAlpha[0];
  const float scale = 1.0f / (9.0f * alpha);
  const int bm = blockIdx.x >> 6, bn = blockIdx.x & 63;
  const int t = threadIdx.x;
  const int tx = t & 15, ty = t >> 4;
  float acc[4][4] = {};
  for (int k0 = 0; k0 < KDIM; k0 += 16) {
    int r = t >> 2;
#pragma unroll
    for (int i = 0; i < 4; ++i) {
      int c = (t & 3) * 4 + i;
      As[r][c] = X[(size_t)(bm * 64 + r) * KDIM + k0 + c];
      float w = W[(size_t)(bn * 64 + r) * KDIM + k0 + c];
      Ws[r][c] = quant_wint(w, alpha) * scale;
    }
    __syncthreads();
#pragma unroll
    for (int kk = 0; kk < 16; ++kk)
#pragma unroll
      for (int i = 0; i < 4; ++i)
#pragma unroll
        for (int j = 0; j < 4; ++j)
          acc[i][j] += As[ty * 4 + i][kk] * Ws[tx * 4 + j][kk];
    __syncthreads();
  }
#pragma unroll
  for (int i = 0; i < 4; ++i)
#pragma unroll
    for (int j = 0; j < 4; ++j)
      out[(size_t)(bm * 64 + ty * 4 + i) * NDIM + bn * 64 + tx * 4 + j] = acc[i][j];
}

// ---------- launch ----------

extern "C" void kernel_launch(void* const* d_in, const int* in_sizes, int n_in,
                              void* d_out, int out_size, void* d_ws, size_t ws_size,
                              hipStream_t stream) {
  const float* x = (const float*)d_in[0];       // [16384,4096]
  const float* w = (const float*)d_in[1];       // [4096,4096]
  const float* alpha = (const float*)d_in[2];   // scalar
  float* out = (float*)d_out;

  const size_t WQ_BYTES = (size_t)NDIM * KDIM * 2;          // 33.5 MB
  const size_t XP_BYTES = (size_t)MDIM * KDIM * 2;          // 134 MB
  const size_t NEED = WQ_BYTES + XP_BYTES;                  // ~168 MB

  if (ws_size >= NEED) {
    u16* Wq = (u16*)d_ws;
    u16* Xh = (u16*)((char*)d_ws + WQ_BYTES);
    quant_w_kernel<<<(NDIM * KDIM / 8) / 256, 256, 0, stream>>>(
        (const float4*)w, alpha, Wq);
    cvt_x_kernel<<<(MDIM * KDIM / 8) / 256, 256, 0, stream>>>(
        (const float4*)x, Xh);
    qgemm_kernel<<<(MDIM / BM) * (NDIM / BN), 512, 0, stream>>>(
        Xh, Wq, alpha, out);
  } else {
    fb_gemm_kernel<<<(MDIM / 64) * (NDIM / 64), 256, 0, stream>>>(x, w, alpha, out);
  }
}

// Round 5
// 528.998 us; speedup vs baseline: 1.9604x; 1.0282x over previous
//
#include <hip/hip_runtime.h>

// QuantizedLinear: out[b,s,o] = sum_k x[b,s,k] * qw[o,k]
// qw in {-2,-1,0,1,2}/(9*alpha) -> single-plane bf16 MFMA GEMM.
// M=16384, N=4096, K=4096. fp32 in/out.
//
// R5: 256x256 BK=64, 4 phases/K-tile, ONE barrier + ONE vmcnt(4) per K-tile.
//   Waves drift within a tile -> wave B's MFMA cluster covers wave A's
//   ds_read drain (anti-phasing; setprio arbitrates). Staging: A triple-
//   buffered (HBM-streamed, 4-phase lead), B double-buffered (L3-hot,
//   2-phase lead) = 160 KiB LDS. Per-wave lgkm/vm gates remain correct
//   under drift; cross-wave RAW transferred by the single tile-end barrier.
// Prepasses: K-chunk XOR pre-swizzled global layout -> linear global_load_lds
// + swizzled ds_read_b128 (0 bank conflicts measured).

typedef unsigned short u16;
typedef unsigned int u32;
typedef __bf16 bf16x8 __attribute__((ext_vector_type(8)));
typedef float f32x4 __attribute__((ext_vector_type(4)));

#define MDIM 16384
#define NDIM 4096
#define KDIM 4096

// ---------- helpers ----------

__device__ __forceinline__ u16 f2bf(float x) {
  u32 u = __float_as_uint(x);
  return (u16)((u + 0x7FFFu + ((u >> 16) & 1u)) >> 16);
}

__device__ __forceinline__ float quant_wint(float w, float alpha) {
  // nearest of {3.5,4.0,4.5,5.0,5.5} to 4.5*(1+w*alpha); argmin tie -> lower level.
  float tv = 4.5f * (1.0f + w * alpha);
  float u = (tv - 3.5f) * 2.0f;
  float f = ceilf(u - 0.5f);
  f = fminf(fmaxf(f, 0.0f), 4.0f);
  return f - 2.0f;                  // Wint in {-2..2}; scale 1/(9*alpha) in epilogue
}

__device__ __forceinline__ void gld16(const void* g, void* l) {
  __builtin_amdgcn_global_load_lds(
      (const __attribute__((address_space(1))) void*)g,
      (__attribute__((address_space(3))) void*)l, 16, 0, 0);
}

// ---------- prepass: quantize weight, swizzled store ----------

__global__ void quant_w_kernel(const float4* __restrict__ W,
                               const float* __restrict__ pAlpha,
                               u16* __restrict__ Wq) {
  float alpha = pAlpha[0];
  u32 g = blockIdx.x * 256u + threadIdx.x;
  u32 n = g >> 9, bw = g & 511u;
  u32 dbw = (bw & ~7u) | ((bw & 7u) ^ (n & 7u));
  float4 a = W[(size_t)g * 2];
  float4 b = W[(size_t)g * 2 + 1];
  float v[8] = {a.x, a.y, a.z, a.w, b.x, b.y, b.z, b.w};
  u32 o[4];
#pragma unroll
  for (int p = 0; p < 4; ++p) {
    u16 l0 = f2bf(quant_wint(v[2 * p], alpha));
    u16 l1 = f2bf(quant_wint(v[2 * p + 1], alpha));
    o[p] = (u32)l0 | ((u32)l1 << 16);
  }
  *(uint4*)&Wq[(size_t)n * 4096 + (size_t)dbw * 8] = make_uint4(o[0], o[1], o[2], o[3]);
}

// ---------- prepass: x -> bf16, swizzled store ----------

__global__ void cvt_x_kernel(const float4* __restrict__ X, u16* __restrict__ Xh) {
  u32 g = blockIdx.x * 256u + threadIdx.x;
  u32 m = g >> 9, bw = g & 511u;
  u32 dbw = (bw & ~7u) | ((bw & 7u) ^ (m & 7u));
  float4 a = X[(size_t)g * 2];
  float4 b = X[(size_t)g * 2 + 1];
  float v[8] = {a.x, a.y, a.z, a.w, b.x, b.y, b.z, b.w};
  u32 oh[4];
#pragma unroll
  for (int p = 0; p < 4; ++p) {
    u16 h0 = f2bf(v[2 * p]);
    u16 h1 = f2bf(v[2 * p + 1]);
    oh[p] = (u32)h0 | ((u32)h1 << 16);
  }
  *(uint4*)&Xh[(size_t)m * 4096 + (size_t)dbw * 8] = make_uint4(oh[0], oh[1], oh[2], oh[3]);
}

// ---------- main GEMM: 256x256, BK=64, drift-scheduled ----------

#define BM 256
#define BN 256
#define BK 64
#define NKT (KDIM / BK)   // 64

// LDS byte map: Abuf p (p=0..2): p*32768 ; Bbuf q (q=0..1): 98304 + q*32768
// element map:  Abuf p: p*16384  ; Bbuf q: 49152 + q*16384 ; half H: +8192 elems

__global__ __launch_bounds__(512, 2) void qgemm_kernel(
    const u16* __restrict__ Xh, const u16* __restrict__ Wq,
    const float* __restrict__ pAlpha, float* __restrict__ out) {
  __shared__ __align__(16) u16 sm[81920];   // 160 KiB
  const char* smb = (const char*)sm;

  const int t512 = threadIdx.x;
  const int lane = t512 & 63;
  const int wave = t512 >> 6;
  const int wm = wave >> 2;      // 0..1
  const int wn = wave & 3;       // 0..3

  // XCD-chunked swizzle: nwg=1024, 8 XCDs, 128 per chunk
  const int bid = blockIdx.x;
  const int nid = (bid & 7) * 128 + (bid >> 3);
  const int m_idx = nid >> 4;    // 64 M-tiles
  const int n_idx = nid & 15;    // 16 N-tiles (consecutive nid share A panel)
  const int m0 = m_idx * BM, n0 = n_idx * BN;

  const float alpha = pAlpha[0];

  f32x4 acc[8][4] = {};
  bf16x8 bfr[4];

  const int kb = (lane >> 4) << 4;     // byte offset of k-group within 128B row
  const int swz = (lane & 7) << 4;     // XOR swizzle (matches prepass layout)

  // frag row maps (interleaved across halves: mi>>2 / nj>>1 select the half)
#define AROW(MI) (wm * 64 + ((MI) >> 2) * 128 + ((MI)&3) * 16 + (lane & 15))
#define BROW(NJ) (wn * 32 + ((NJ) >> 1) * 128 + ((NJ)&1) * 16 + (lane & 15))
#define LDA(AB, MI, KS) \
  (*(const bf16x8*)(smb + (AB) + AROW(MI) * 128 + ((((KS)*64) + kb) ^ swz)))
#define LDB(BB, NJ, KS) \
  (*(const bf16x8*)(smb + (BB) + BROW(NJ) * 128 + ((((KS)*64) + kb) ^ swz)))

  // global row-block bases for half-tiles of k-tile KT (wrapped; junk tail
  // only ever lands in buffers that are never read again)
#define GA(KT, H) (Xh + (size_t)(m0 + (H)*128) * 4096 + (size_t)(((KT)&63)) * 64)
#define GB(KT, H) (Wq + (size_t)(n0 + (H)*128) * 4096 + (size_t)(((KT)&63)) * 64)

  // stage one 128x64 half-tile: 2 x global_load_lds(16B), linear dest
#define STAGE(GBASE, LELEM) do { \
    const u16* _g = (GBASE) + (size_t)(wave * 8 + (lane >> 3)) * 4096 + (size_t)((lane & 7) * 8); \
    gld16(_g, (void*)(sm + (LELEM) + wave * 512)); \
    gld16(_g + (size_t)64 * 4096, (void*)(sm + (LELEM) + 4096 + wave * 512)); \
  } while (0)

#define ACCROW(MI, AV) do { \
    acc[MI][0] = __builtin_amdgcn_mfma_f32_16x16x32_bf16(AV, bfr[0], acc[MI][0], 0, 0, 0); \
    acc[MI][1] = __builtin_amdgcn_mfma_f32_16x16x32_bf16(AV, bfr[1], acc[MI][1], 0, 0, 0); \
    acc[MI][2] = __builtin_amdgcn_mfma_f32_16x16x32_bf16(AV, bfr[2], acc[MI][2], 0, 0, 0); \
    acc[MI][3] = __builtin_amdgcn_mfma_f32_16x16x32_bf16(AV, bfr[3], acc[MI][3], 0, 0, 0); \
  } while (0)

  // phase: reads + 1 half-tile stage + per-wave lgkm gate + 16 MFMA.
  // NO barrier, NO vm wait here -> waves drift within the K-tile.
#define PHASE(AB, BB, KS, MH, READB, SG, SL) do { \
    if (READB) { \
      bfr[0] = LDB(BB, 0, KS); bfr[1] = LDB(BB, 1, KS); \
      bfr[2] = LDB(BB, 2, KS); bfr[3] = LDB(BB, 3, KS); \
    } \
    bf16x8 a0 = LDA(AB, (MH)*4 + 0, KS); \
    bf16x8 a1 = LDA(AB, (MH)*4 + 1, KS); \
    bf16x8 a2 = LDA(AB, (MH)*4 + 2, KS); \
    bf16x8 a3 = LDA(AB, (MH)*4 + 3, KS); \
    STAGE(SG, SL); \
    __builtin_amdgcn_sched_barrier(0); \
    asm volatile("s_waitcnt lgkmcnt(0)" ::: "memory"); \
    __builtin_amdgcn_sched_barrier(0); \
    __builtin_amdgcn_s_setprio(1); \
    ACCROW((MH)*4 + 0, a0); ACCROW((MH)*4 + 1, a1); \
    ACCROW((MH)*4 + 2, a2); ACCROW((MH)*4 + 3, a3); \
    __builtin_amdgcn_s_setprio(0); \
  } while (0)

#define TILEGATE do { \
    asm volatile("s_waitcnt vmcnt(4)" ::: "memory"); \
    __builtin_amdgcn_s_barrier(); \
  } while (0)

  // prologue: B(0)->Bbuf0, A(0)->Abuf0, A(1)->Abuf1 (12 loads);
  // vm4 leaves A(1) in flight = steady state.
  STAGE(GB(0, 0), 49152);
  STAGE(GB(0, 1), 49152 + 8192);
  STAGE(GA(0, 0), 0);
  STAGE(GA(0, 1), 8192);
  STAGE(GA(1, 0), 16384);
  STAGE(GA(1, 1), 16384 + 8192);
  asm volatile("s_waitcnt vmcnt(4)" ::: "memory");
  __builtin_amdgcn_s_barrier();

  // rotating A-buffer byte/elem bases: cur=(t)%3, nxt=(t+1)%3, st2=(t+2)%3
  int aC = 0, aN = 32768, aS = 65536;

#pragma unroll 1
  for (int t = 0; t < NKT; t += 2) {
    const int aCe = aC >> 1, aSe = aS >> 1;   // element offsets
    // tile t: reads Abuf aC + Bbuf0; stages B(t+1)->Bbuf1, A(t+2)->Abuf aS
    PHASE(aC, 98304, 0, 0, 1, GB(t + 1, 0), 65536);
    PHASE(aC, 98304, 0, 1, 0, GB(t + 1, 1), 65536 + 8192);
    PHASE(aC, 98304, 1, 0, 1, GA(t + 2, 0), aSe);
    PHASE(aC, 98304, 1, 1, 0, GA(t + 2, 1), aSe + 8192);
    TILEGATE;   // A(t+1),B(t+1) landed; A(t+2) in flight
    // tile t+1: reads Abuf aN + Bbuf1; stages B(t+2)->Bbuf0, A(t+3)->Abuf aC
    PHASE(aN, 131072, 0, 0, 1, GB(t + 2, 0), 49152);
    PHASE(aN, 131072, 0, 1, 0, GB(t + 2, 1), 49152 + 8192);
    PHASE(aN, 131072, 1, 0, 1, GA(t + 3, 0), aCe);
    PHASE(aN, 131072, 1, 1, 0, GA(t + 3, 1), aCe + 8192);
    TILEGATE;   // A(t+2),B(t+2) landed; A(t+3) in flight
    // rotate: new (cur,nxt,st2) = (st2,cur,nxt)
    int tmp = aC; aC = aS; aS = aN; aN = tmp;
  }

  // epilogue
  const float scale = 1.0f / (9.0f * alpha);
#pragma unroll
  for (int mi = 0; mi < 8; ++mi) {
    int row = m0 + (mi >> 2) * 128 + wm * 64 + (mi & 3) * 16 + (lane >> 4) * 4;
#pragma unroll
    for (int nj = 0; nj < 4; ++nj) {
      int col = n0 + (nj >> 1) * 128 + wn * 32 + (nj & 1) * 16 + (lane & 15);
#pragma unroll
      for (int r = 0; r < 4; ++r)
        out[(size_t)(row + r) * NDIM + col] = acc[mi][nj][r] * scale;
    }
  }
#undef TILEGATE
#undef PHASE
#undef ACCROW
#undef STAGE
#undef GA
#undef GB
#undef LDA
#undef LDB
#undef AROW
#undef BROW
}

// ---------- fallback (ws too small): fp32 tiled GEMM, quant on the fly ----------

__global__ void fb_gemm_kernel(const float* __restrict__ X, const float* __restrict__ W,
                               const float* __restrict__ pAlpha, float* __restrict__ out) {
  __shared__ float As[64][17];
  __shared__ float Ws[64][17];
  const float alpha = pAlpha[0];
  const float scale = 1.0f / (9.0f * alpha);
  const int bm = blockIdx.x >> 6, bn = blockIdx.x & 63;
  const int t = threadIdx.x;
  const int tx = t & 15, ty = t >> 4;
  float acc[4][4] = {};
  for (int k0 = 0; k0 < KDIM; k0 += 16) {
    int r = t >> 2;
#pragma unroll
    for (int i = 0; i < 4; ++i) {
      int c = (t & 3) * 4 + i;
      As[r][c] = X[(size_t)(bm * 64 + r) * KDIM + k0 + c];
      float w = W[(size_t)(bn * 64 + r) * KDIM + k0 + c];
      Ws[r][c] = quant_wint(w, alpha) * scale;
    }
    __syncthreads();
#pragma unroll
    for (int kk = 0; kk < 16; ++kk)
#pragma unroll
      for (int i = 0; i < 4; ++i)
#pragma unroll
        for (int j = 0; j < 4; ++j)
          acc[i][j] += As[ty * 4 + i][kk] * Ws[tx * 4 + j][kk];
    __syncthreads();
  }
#pragma unroll
  for (int i = 0; i < 4; ++i)
#pragma unroll
    for (int j = 0; j < 4; ++j)
      out[(size_t)(bm * 64 + ty * 4 + i) * NDIM + bn * 64 + tx * 4 + j] = acc[i][j];
}

// ---------- launch ----------

extern "C" void kernel_launch(void* const* d_in, const int* in_sizes, int n_in,
                              void* d_out, int out_size, void* d_ws, size_t ws_size,
                              hipStream_t stream) {
  const float* x = (const float*)d_in[0];       // [16384,4096]
  const float* w = (const float*)d_in[1];       // [4096,4096]
  const float* alpha = (const float*)d_in[2];   // scalar
  float* out = (float*)d_out;

  const size_t WQ_BYTES = (size_t)NDIM * KDIM * 2;          // 33.5 MB
  const size_t XP_BYTES = (size_t)MDIM * KDIM * 2;          // 134 MB
  const size_t NEED = WQ_BYTES + XP_BYTES;                  // ~168 MB

  if (ws_size >= NEED) {
    u16* Wq = (u16*)d_ws;
    u16* Xh = (u16*)((char*)d_ws + WQ_BYTES);
    quant_w_kernel<<<(NDIM * KDIM / 8) / 256, 256, 0, stream>>>(
        (const float4*)w, alpha, Wq);
    cvt_x_kernel<<<(MDIM * KDIM / 8) / 256, 256, 0, stream>>>(
        (const float4*)x, Xh);
    qgemm_kernel<<<(MDIM / BM) * (NDIM / BN), 512, 0, stream>>>(
        Xh, Wq, alpha, out);
  } else {
    fb_gemm_kernel<<<(MDIM / 64) * (NDIM / 64), 256, 0, stream>>>(x, w, alpha, out);
  }
}